// Round 11
// baseline (201.471 us; speedup 1.0000x reference)
//
#include <hip/hip_runtime.h>
#include <hip/hip_bf16.h>
#include <stdint.h>

#define D_MODEL 1024
#define NUM_EXPERTS 8
#define NBUCKET 16            // 8 primary + 8 secondary virtual experts
#define BM 128
#define BN 128
#define BK 64
#define KSTEPS (D_MODEL / BK)   // 16
#define GATE_TOK 8            // tokens per gate work: 1024 gate blocks
#define GATE_BLOCKS_N 1024    // T / GATE_TOK (T = 8192)
#define NSEG (NUM_EXPERTS * KSTEPS * 1024 * 8)   // 1048576 16B-segments
#define CONV_BLOCKS_N (NSEG / 256)               // 4096

typedef __bf16 bf16x8 __attribute__((ext_vector_type(8)));
typedef float f32x4 __attribute__((ext_vector_type(4)));
typedef unsigned short u16x8 __attribute__((ext_vector_type(8)));

__device__ __forceinline__ unsigned short f32_to_bf16_rne(float f) {
    union { float f; uint32_t u; } v;
    v.f = f;
    uint32_t u = v.u;
    u += 0x7FFFu + ((u >> 16) & 1u);   // round-to-nearest-even
    return (unsigned short)(u >> 16);
}

__device__ __forceinline__ float bf16_to_f32(unsigned short h) {
    union { uint32_t u; float f; } v;
    v.u = ((uint32_t)h) << 16;
    return v.f;
}

__device__ __forceinline__ void gload_lds16(const unsigned short* g, unsigned short* l) {
    __builtin_amdgcn_global_load_lds(
        (const __attribute__((address_space(1))) void*)g,
        (__attribute__((address_space(3))) void*)l,
        16, 0, 0);
}

// ---------------------------------------------------------------------------
// prep_kernel: gate + We-convert in ONE dispatch (saves one ~15-20us
// dispatch boundary). r9's version of this fusion failed because the gate was
// a 78us straggler wall; the r10 transpose-reduce gate is ~12us, so the
// branches are now balanced. Both branch bodies are byte-identical to the
// r10-verified kernels.
//   blocks [0, 1024):        gate, 8 tokens each (r10 gate-v4 body)
//   blocks [1024, 1024+4096): We fp32->bf16, LINEAR reads (src = g*8),
//                            output wbv[e][kt][n][seg^(n&7)][8]
// ---------------------------------------------------------------------------
__global__ __launch_bounds__(256) void prep_kernel(
    const float* __restrict__ x, const float* __restrict__ Wg,
    const float* __restrict__ bg, const float* __restrict__ We, int T,
    int* __restrict__ counts, int* __restrict__ token_list,
    float* __restrict__ gate_list, unsigned short* __restrict__ xb,
    unsigned short* __restrict__ wbv)
{
    const int tid = threadIdx.x;

    __shared__ double red[4][NUM_EXPERTS][65];   // 16.6 KB, wave-private rows
    __shared__ double logitS[GATE_TOK][NUM_EXPERTS];
    __shared__ int cntS[NBUCKET];
    __shared__ int baseS[NBUCKET];

    if (blockIdx.x >= GATE_BLOCKS_N) {
        // ----------------- convert branch (pure BW, r10 body) -------------
        int g = (blockIdx.x - GATE_BLOCKS_N) * 256 + tid;   // 0 .. NSEG-1
        int s   = g & 7;
        int kt  = (g >> 3) & (KSTEPS - 1);
        int n   = (g >> 7) & 1023;
        int e   = g >> 17;

        const float* sp = We + (size_t)g * 8;    // linear 32B/thread
        float4 a = ((const float4*)sp)[0];
        float4 b = ((const float4*)sp)[1];
        u16x8 o;
        o[0] = f32_to_bf16_rne(a.x);
        o[1] = f32_to_bf16_rne(a.y);
        o[2] = f32_to_bf16_rne(a.z);
        o[3] = f32_to_bf16_rne(a.w);
        o[4] = f32_to_bf16_rne(b.x);
        o[5] = f32_to_bf16_rne(b.y);
        o[6] = f32_to_bf16_rne(b.z);
        o[7] = f32_to_bf16_rne(b.w);

        int ss = s ^ (n & 7);
        unsigned short* dp =
            wbv + (((size_t)(e * KSTEPS + kt) * 1024 + n) * BK) + ss * 8;
        *(u16x8*)dp = o;
        return;
    }

    // ----------------- gate branch (r10-verified gate-v4 body) ------------
    const int lane = tid & 63;
    const int wave = tid >> 6;            // 0..3
    const int tokBase = blockIdx.x * GATE_TOK;

    if (tid < NBUCKET) cntS[tid] = 0;

    const float4* Wg4 = (const float4*)Wg;

    // Load 2 tokens per wave; fuse x fp32->bf16 (RNE) conversion.
    float4 xv[2][4];
#pragma unroll
    for (int t = 0; t < 2; t++) {
        const int token = tokBase + wave * 2 + t;
        const float4* xr4 = (const float4*)(x + (size_t)token * D_MODEL);
        ushort4* xbr4 = (ushort4*)(xb + (size_t)token * D_MODEL);
#pragma unroll
        for (int q = 0; q < 4; q++) {
            float4 f = xr4[q * 64 + lane];
            xv[t][q] = f;
            ushort4 o;
            o.x = f32_to_bf16_rne(f.x);
            o.y = f32_to_bf16_rne(f.y);
            o.z = f32_to_bf16_rne(f.z);
            o.w = f32_to_bf16_rne(f.w);
            xbr4[q * 64 + lane] = o;
        }
    }

    // fp64 partials: Wg loaded once per (e,q), reused across both tokens.
    double acc[2][NUM_EXPERTS];
#pragma unroll
    for (int t = 0; t < 2; t++)
#pragma unroll
        for (int e = 0; e < NUM_EXPERTS; e++) acc[t][e] = 0.0;
#pragma unroll
    for (int e = 0; e < NUM_EXPERTS; e++) {
#pragma unroll
        for (int q = 0; q < 4; q++) {
            float4 w = Wg4[e * 256 + q * 64 + lane];
#pragma unroll
            for (int t = 0; t < 2; t++) {
                acc[t][e] += (double)xv[t][q].x * (double)w.x;
                acc[t][e] += (double)xv[t][q].y * (double)w.y;
                acc[t][e] += (double)xv[t][q].z * (double)w.z;
                acc[t][e] += (double)xv[t][q].w * (double)w.w;
            }
        }
    }

    // LDS transpose-reduce (wave-private region: no __syncthreads needed).
    const int e2 = lane >> 3, g = lane & 7;
#pragma unroll
    for (int t = 0; t < 2; t++) {
#pragma unroll
        for (int e = 0; e < NUM_EXPERTS; e++)
            red[wave][e][lane] = acc[t][e];
        double s = 0.0;
#pragma unroll
        for (int j = 0; j < 8; j++)
            s += red[wave][e2][g * 8 + j];
        s += __shfl_xor(s, 1, 64);
        s += __shfl_xor(s, 2, 64);
        s += __shfl_xor(s, 4, 64);
        if (g == 0)
            logitS[wave * 2 + t][e2] = s + (double)bg[e2];
    }
    __syncthreads();

    // Phase 2: one thread per token — strict top-2 (lower index wins ties,
    // matches lax.top_k) + fp64 softmax + block-aggregated bucket append.
    int i1 = 0, i2 = 0, o1 = 0, o2 = 0;
    double v1d = 0.0, v2d = 0.0;
    const int token2 = tokBase + tid;
    if (tid < GATE_TOK) {
        double lg[NUM_EXPERTS];
#pragma unroll
        for (int e = 0; e < NUM_EXPERTS; e++) lg[e] = logitS[tid][e];
        i1 = 0;
#pragma unroll
        for (int e = 1; e < NUM_EXPERTS; e++) if (lg[e] > lg[i1]) i1 = e;
        i2 = (i1 == 0) ? 1 : 0;
#pragma unroll
        for (int e = 0; e < NUM_EXPERTS; e++)
            if (e != i1 && lg[e] > lg[i2]) i2 = e;
        double m = lg[i1], den = 0.0;
#pragma unroll
        for (int e = 0; e < NUM_EXPERTS; e++) den += exp(lg[e] - m);
        v1d = exp(lg[i1] - m) / den;
        v2d = exp(lg[i2] - m) / den;
        o1 = atomicAdd(&cntS[i1], 1);          // primary bucket e
        o2 = atomicAdd(&cntS[8 + i2], 1);      // secondary bucket 8+e
    }
    __syncthreads();
    if (tid < NBUCKET) baseS[tid] = atomicAdd(&counts[tid], cntS[tid]);
    __syncthreads();
    if (tid < GATE_TOK) {
        int p1 = i1 * T + baseS[i1] + o1;
        token_list[p1] = token2;
        gate_list[p1]  = (float)v1d;
        int p2 = (8 + i2) * T + baseS[8 + i2] + o2;
        token_list[p2] = token2;
        gate_list[p2]  = (float)v2d;
    }
}

// ---------------------------------------------------------------------------
// Per-bucket gathered GEMM (r10-verified 512-thread version, unchanged —
// control): r3 layout/swizzle + counted-vmcnt double-buffer; 8 waves/block,
// wave owns 64x32 sub-tile; stage = 2A+2B 16B loads/thread -> vmcnt(4).
// ---------------------------------------------------------------------------
__global__ __launch_bounds__(512) void moe_gemm(
    const unsigned short* __restrict__ xb,   // [T][1024] bf16
    const unsigned short* __restrict__ wb,   // [E][16][1024][64] bf16, swizzled
    const float* __restrict__ be,            // [E][1024]
    const int* __restrict__ counts,          // [16]
    const int* __restrict__ token_list,      // [16][T]
    const float* __restrict__ gate_list,     // [16][T]
    unsigned short* __restrict__ ybuf,       // [2][T][1024] bf16
    int T)
{
    const int bid = blockIdx.x;
    const int nt = bid & 7;
    const int rest = bid >> 3;
    const int vexp = rest & (NBUCKET - 1);
    const int mt = rest >> 4;
    const int e_w = vexp & 7;

    const int n_e = counts[vexp];
    const int m0 = mt * BM;
    if (m0 >= n_e) return;
    const int n0 = nt * BN;
    const int tid = threadIdx.x;

    __shared__ __align__(16) unsigned short As[2][BM * BK];   // 2 x 16 KB
    __shared__ __align__(16) unsigned short Bs[2][BN * BK];   // 2 x 16 KB
    __shared__ int   tokS[BM];
    __shared__ float gateS[BM];

    if (tid < BM) {
        int r = m0 + tid;
        int tk = 0; float gv = 0.f;
        if (r < n_e) {
            tk = token_list[vexp * T + r];
            gv = gate_list[vexp * T + r];
        }
        tokS[tid]  = tk;
        gateS[tid] = gv;
    }
    __syncthreads();

    const unsigned short* asrc[2];
#pragma unroll
    for (int i = 0; i < 2; i++) {
        int flat = i * 512 + tid;
        int r = flat >> 3, seg = flat & 7;
        int ss = seg ^ (r & 7);
        asrc[i] = xb + (size_t)tokS[r] * D_MODEL + ss * 8;
    }
    const unsigned short* bsrc =
        wb + (size_t)e_w * (KSTEPS * 1024 * BK) + (size_t)n0 * BK;

    const int wave = tid >> 6, lane = tid & 63;
    const int wm = (wave >> 2) * 64, wn = (wave & 3) * 32;
    const int frow = lane & 15;
    const int qq = lane >> 4;
    const int sw8 = frow & 7;

    f32x4 acc[4][2];
#pragma unroll
    for (int mi = 0; mi < 4; mi++)
#pragma unroll
        for (int ni = 0; ni < 2; ni++)
            acc[mi][ni] = (f32x4){0.f, 0.f, 0.f, 0.f};

    // Prologue: stage K-tile 0 into buffer 0 (4 vm ops; waited in-loop).
#pragma unroll
    for (int i = 0; i < 2; i++) {
        int flat = i * 512 + tid;
        gload_lds16(asrc[i], &As[0][flat * 8]);
        gload_lds16(bsrc + flat * 8, &Bs[0][flat * 8]);
    }

#pragma unroll 2
    for (int kt = 0; kt < KSTEPS; kt++) {
        const int cur = kt & 1;
        if (kt + 1 < KSTEPS) {
#pragma unroll
            for (int i = 0; i < 2; i++) {
                int flat = i * 512 + tid;
                gload_lds16(asrc[i] + (kt + 1) * BK, &As[cur ^ 1][flat * 8]);
                gload_lds16(bsrc + (size_t)(kt + 1) * (1024 * BK) + flat * 8,
                            &Bs[cur ^ 1][flat * 8]);
            }
            asm volatile("s_waitcnt vmcnt(4)" ::: "memory");  // tile k done
        } else {
            asm volatile("s_waitcnt vmcnt(0)" ::: "memory");  // tail
        }
        __builtin_amdgcn_sched_barrier(0);
        __builtin_amdgcn_s_barrier();          // all waves: tile k in LDS
        __builtin_amdgcn_sched_barrier(0);

#pragma unroll
        for (int ks = 0; ks < 2; ks++) {
            const int off = ((ks * 4 + qq) ^ sw8) * 8;   // swizzled k-offset
            bf16x8 af[4], bfv[2];
#pragma unroll
            for (int mi = 0; mi < 4; mi++)
                af[mi] = *(const bf16x8*)&As[cur][(wm + mi * 16 + frow) * BK + off];
#pragma unroll
            for (int ni = 0; ni < 2; ni++)
                bfv[ni] = *(const bf16x8*)&Bs[cur][(wn + ni * 16 + frow) * BK + off];
#pragma unroll
            for (int mi = 0; mi < 4; mi++)
#pragma unroll
                for (int ni = 0; ni < 2; ni++)
                    acc[mi][ni] = __builtin_amdgcn_mfma_f32_16x16x32_bf16(
                        af[mi], bfv[ni], acc[mi][ni], 0, 0, 0);
        }
        __builtin_amdgcn_sched_barrier(0);
        __builtin_amdgcn_s_barrier();          // buf[cur] free for stage(k+2)
        __builtin_amdgcn_sched_barrier(0);
    }

    // Epilogue: C/D layout col = lane&15, row = (lane>>4)*4 + reg.
    unsigned short* ybase = ybuf + (size_t)(vexp >> 3) * T * D_MODEL;
    const int rbase = (lane >> 4) * 4;
    const int col   = lane & 15;
#pragma unroll
    for (int mi = 0; mi < 4; mi++) {
#pragma unroll
        for (int r = 0; r < 4; r++) {
            int lrow = wm + mi * 16 + rbase + r;
            if (m0 + lrow < n_e) {
                int   tk = tokS[lrow];
                float gv = gateS[lrow];
                unsigned short* yr = ybase + (size_t)tk * D_MODEL;
#pragma unroll
                for (int ni = 0; ni < 2; ni++) {
                    int c = n0 + wn + ni * 16 + col;
                    float val = gv * (acc[mi][ni][r] + be[e_w * D_MODEL + c]);
                    yr[c] = f32_to_bf16_rne(val);
                }
            }
        }
    }
}

// ---------------------------------------------------------------------------
// Combine: out[t][d] = ybuf[0][t][d] + ybuf[1][t][d]  (bf16 -> fp32 add)
// Grid-stride at 2048 blocks (kills the 8192-block dispatch ramp).
// ---------------------------------------------------------------------------
__global__ __launch_bounds__(256) void combine_kernel(
    const unsigned short* __restrict__ y0,
    const unsigned short* __restrict__ y1,
    float* __restrict__ out, int n4)
{
    for (int i = blockIdx.x * 256 + threadIdx.x; i < n4; i += 2048 * 256) {
        ushort4 a = ((const ushort4*)y0)[i];
        ushort4 b = ((const ushort4*)y1)[i];
        float4 o;
        o.x = bf16_to_f32(a.x) + bf16_to_f32(b.x);
        o.y = bf16_to_f32(a.y) + bf16_to_f32(b.y);
        o.z = bf16_to_f32(a.z) + bf16_to_f32(b.z);
        o.w = bf16_to_f32(a.w) + bf16_to_f32(b.w);
        ((float4*)out)[i] = o;
    }
}

extern "C" void kernel_launch(void* const* d_in, const int* in_sizes, int n_in,
                              void* d_out, int out_size, void* d_ws, size_t ws_size,
                              hipStream_t stream) {
    const float* x  = (const float*)d_in[0];
    const float* Wg = (const float*)d_in[1];
    const float* bg = (const float*)d_in[2];
    const float* We = (const float*)d_in[3];
    const float* be = (const float*)d_in[4];
    // top_k (d_in[5]) is fixed at 2 per the reference; hard-coded.

    const int T = in_sizes[0] / D_MODEL;   // 8192 tokens

    // workspace carve-up (~68 MB total)
    char* ws = (char*)d_ws;
    unsigned short* xb = (unsigned short*)ws;                       // T*D bf16
    size_t off = (size_t)T * D_MODEL * 2;
    unsigned short* wbv = (unsigned short*)(ws + off);              // E*D*D bf16
    off += (size_t)NUM_EXPERTS * D_MODEL * D_MODEL * 2;
    int* counts = (int*)(ws + off);         off += 256;
    int* token_list = (int*)(ws + off);     off += (size_t)NBUCKET * T * 4;
    float* gate_list = (float*)(ws + off);  off += (size_t)NBUCKET * T * 4;
    unsigned short* ybuf = (unsigned short*)(ws + off);             // 2*T*D bf16
    off += (size_t)2 * T * D_MODEL * 2;

    hipMemsetAsync(counts, 0, 256, stream);

    prep_kernel<<<GATE_BLOCKS_N + CONV_BLOCKS_N, 256, 0, stream>>>(
        x, Wg, bg, We, T, counts, token_list, gate_list, xb, wbv);

    const int MT = (T + BM - 1) / BM;       // worst case: all tokens in one bucket
    moe_gemm<<<MT * NBUCKET * 8, 512, 0, stream>>>(
        xb, wbv, be, counts, token_list, gate_list, ybuf, T);

    int n4c = T * D_MODEL / 4;
    combine_kernel<<<2048, 256, 0, stream>>>(
        ybuf, ybuf + (size_t)T * D_MODEL, (float*)d_out, n4c);
}